// Round 4
// baseline (365.266 us; speedup 1.0000x reference)
//
#include <hip/hip_runtime.h>

// ROI pooling (bilinear crop-and-resize to 9x9), TF2 half-pixel semantics.
// feature_map: [B=4, H=256, W=256, C=256] f32 (NHWC)
// rois:        [B, R=128, 4] int32 = (x, y, w, h)
// out:         [B, R, 9, 9, C] f32
//
// ROUND 4 = MEASUREMENT ROUND. Kernel body is byte-identical to round 3;
// kernel_launch launches it TWICE (idempotent — second launch rewrites the
// same values). dur_us_new - dur_us_old directly measures one (warm) kernel
// execution, separating kernel time from the ~251us of per-iteration harness
// overhead (1GiB ws poison + 256MB d_in restore + d_out poison) that the
// rocprof top-5 shows dominating the timed loop.

#define PH 9
#define PW 9
#define TPB 256
#define NBLK 2048   // 8192 persistent waves; 41472 cells -> ~5 cells/wave

typedef float f32x4 __attribute__((ext_vector_type(4)));

struct Cell {
    const f32x4* p00;
    const f32x4* p01;
    const f32x4* p10;
    const f32x4* p11;
    float fx, fy;
};

__device__ inline Cell cell_addrs(int cell, int lane,
                                  const float* __restrict__ fm,
                                  const int* __restrict__ rois,
                                  int H, int W, int C, int R)
{
    Cell c;
    int px = cell % PW;
    int t  = cell / PW;
    int py = t % PH;
    t /= PH;
    const int r = t % R;
    const int b = t / R;

    const int* roi = rois + (b * R + r) * 4;
    const int rx = roi[0];
    const int ry = roi[1];
    const int rw = roi[2];
    const int rh = roi[3];

    const float hf = (float)rh;
    const float wf = (float)rw;

    // Match reference op order exactly: (i+0.5)*(hf/PH)-0.5, clamp [0, hf-1]
    float sy = ((float)py + 0.5f) * (hf / (float)PH) - 0.5f;
    float sx = ((float)px + 0.5f) * (wf / (float)PW) - 0.5f;
    sy = fminf(fmaxf(sy, 0.0f), hf - 1.0f);
    sx = fminf(fmaxf(sx, 0.0f), wf - 1.0f);

    const float y0f = floorf(sy);
    const float x0f = floorf(sx);
    c.fy = sy - y0f;
    c.fx = sx - x0f;
    const int y0 = (int)y0f;
    const int x0 = (int)x0f;
    const int y1 = min(y0 + 1, rh - 1);
    const int x1 = min(x0 + 1, rw - 1);

    const long ya0 = (long)ry + y0;
    const long ya1 = (long)ry + y1;
    const long xa0 = (long)rx + x0;
    const long xa1 = (long)rx + x1;

    const long base_b = (long)b * H;
    c.p00 = (const f32x4*)(fm + ((base_b + ya0) * W + xa0) * C) + lane;
    c.p01 = (const f32x4*)(fm + ((base_b + ya0) * W + xa1) * C) + lane;
    c.p10 = (const f32x4*)(fm + ((base_b + ya1) * W + xa0) * C) + lane;
    c.p11 = (const f32x4*)(fm + ((base_b + ya1) * W + xa1) * C) + lane;
    return c;
}

__global__ __launch_bounds__(TPB) void roi_pool_kernel(
    const float* __restrict__ fm,
    const int*   __restrict__ rois,
    float*       __restrict__ out,
    int B, int H, int W, int C, int R)
{
    const int lane   = threadIdx.x & 63;
    const int nwaves = (NBLK * TPB) >> 6;
    const int ncells = B * R * PH * PW;

    int cell = (int)((blockIdx.x * TPB + threadIdx.x) >> 6);
    cell = __builtin_amdgcn_readfirstlane(cell);   // wave-uniform: scalarize addr math
    if (cell >= ncells) return;

    Cell cur = cell_addrs(cell, lane, fm, rois, H, W, C, R);
    f32x4 v00 = *cur.p00;
    f32x4 v01 = *cur.p01;
    f32x4 v10 = *cur.p10;
    f32x4 v11 = *cur.p11;

    while (true) {
        const int nxt = cell + nwaves;
        const bool has = (nxt < ncells);

        Cell nx;
        f32x4 w00, w01, w10, w11;
        if (has) {
            // Issue next cell's loads BEFORE consuming current cell's values.
            nx = cell_addrs(nxt, lane, fm, rois, H, W, C, R);
            w00 = *nx.p00;
            w01 = *nx.p01;
            w10 = *nx.p10;
            w11 = *nx.p11;
        }

        const float fx = cur.fx, fy = cur.fy;
        const float gx = 1.0f - fx;
        const float gy = 1.0f - fy;
        f32x4 o = (v00 * gx + v01 * fx) * gy + (v10 * gx + v11 * fx) * fy;

        f32x4* po = (f32x4*)(out + (long)cell * C) + lane;
        __builtin_nontemporal_store(o, po);

        if (!has) break;
        cell = nxt;
        cur  = nx;
        v00 = w00; v01 = w01; v10 = w10; v11 = w11;
    }
}

extern "C" void kernel_launch(void* const* d_in, const int* in_sizes, int n_in,
                              void* d_out, int out_size, void* d_ws, size_t ws_size,
                              hipStream_t stream) {
    const float* fm   = (const float*)d_in[0];
    const int*   rois = (const int*)d_in[1];
    float*       out  = (float*)d_out;

    const int B = 4, H = 256, W = 256, C = 256, R = 128;

    // Launch TWICE: delta vs round 3's dur_us isolates one kernel execution.
    roi_pool_kernel<<<NBLK, TPB, 0, stream>>>(fm, rois, out, B, H, W, C, R);
    roi_pool_kernel<<<NBLK, TPB, 0, stream>>>(fm, rois, out, B, H, W, C, R);
}

// Round 5
// 334.323 us; speedup vs baseline: 1.0926x; 1.0926x over previous
//
#include <hip/hip_runtime.h>

// ROI pooling (bilinear crop-and-resize to 9x9), TF2 half-pixel semantics.
// feature_map: [B=4, H=256, W=256, C=256] f32 (NHWC)
// rois:        [B, R=128, 4] int32 = (x, y, w, h)
// out:         [B, R, 9, 9, C] f32
//
// FINAL: single launch. Round-4 double-launch probe measured one warm kernel
// execution at 30.0 us (365.3 - 335.2). Compulsory traffic = 166 MB corner
// reads + 42.5 MB writes = 209 MB -> 7.0 TB/s effective, >= the 6.3 TB/s
// achievable HBM BW (L3 serves part of the reads). Kernel is memory-bound at
// the roofline; the remaining ~305 us of dur_us is harness overhead (1 GiB
// ws-poison fills at 82% peak + 256 MB d_in restore), not kernel time.
//
// Structure: one wave (64 lanes) per pooling cell, lane -> 4 channels
// (float4 = 1KB coalesced wave transaction per corner). Persistent waves,
// 2-deep software pipeline; wave-uniform addressing via readfirstlane;
// nontemporal stores for the write-once output stream.

#define PH 9
#define PW 9
#define TPB 256
#define NBLK 2048   // 8192 persistent waves; 41472 cells -> ~5 cells/wave

typedef float f32x4 __attribute__((ext_vector_type(4)));

struct Cell {
    const f32x4* p00;
    const f32x4* p01;
    const f32x4* p10;
    const f32x4* p11;
    float fx, fy;
};

__device__ inline Cell cell_addrs(int cell, int lane,
                                  const float* __restrict__ fm,
                                  const int* __restrict__ rois,
                                  int H, int W, int C, int R)
{
    Cell c;
    int px = cell % PW;
    int t  = cell / PW;
    int py = t % PH;
    t /= PH;
    const int r = t % R;
    const int b = t / R;

    const int* roi = rois + (b * R + r) * 4;
    const int rx = roi[0];
    const int ry = roi[1];
    const int rw = roi[2];
    const int rh = roi[3];

    const float hf = (float)rh;
    const float wf = (float)rw;

    // Match reference op order exactly: (i+0.5)*(hf/PH)-0.5, clamp [0, hf-1]
    float sy = ((float)py + 0.5f) * (hf / (float)PH) - 0.5f;
    float sx = ((float)px + 0.5f) * (wf / (float)PW) - 0.5f;
    sy = fminf(fmaxf(sy, 0.0f), hf - 1.0f);
    sx = fminf(fmaxf(sx, 0.0f), wf - 1.0f);

    const float y0f = floorf(sy);
    const float x0f = floorf(sx);
    c.fy = sy - y0f;
    c.fx = sx - x0f;
    const int y0 = (int)y0f;
    const int x0 = (int)x0f;
    const int y1 = min(y0 + 1, rh - 1);
    const int x1 = min(x0 + 1, rw - 1);

    const long ya0 = (long)ry + y0;
    const long ya1 = (long)ry + y1;
    const long xa0 = (long)rx + x0;
    const long xa1 = (long)rx + x1;

    const long base_b = (long)b * H;
    c.p00 = (const f32x4*)(fm + ((base_b + ya0) * W + xa0) * C) + lane;
    c.p01 = (const f32x4*)(fm + ((base_b + ya0) * W + xa1) * C) + lane;
    c.p10 = (const f32x4*)(fm + ((base_b + ya1) * W + xa0) * C) + lane;
    c.p11 = (const f32x4*)(fm + ((base_b + ya1) * W + xa1) * C) + lane;
    return c;
}

__global__ __launch_bounds__(TPB) void roi_pool_kernel(
    const float* __restrict__ fm,
    const int*   __restrict__ rois,
    float*       __restrict__ out,
    int B, int H, int W, int C, int R)
{
    const int lane   = threadIdx.x & 63;
    const int nwaves = (NBLK * TPB) >> 6;
    const int ncells = B * R * PH * PW;

    int cell = (int)((blockIdx.x * TPB + threadIdx.x) >> 6);
    cell = __builtin_amdgcn_readfirstlane(cell);   // wave-uniform: scalarize addr math
    if (cell >= ncells) return;

    Cell cur = cell_addrs(cell, lane, fm, rois, H, W, C, R);
    f32x4 v00 = *cur.p00;
    f32x4 v01 = *cur.p01;
    f32x4 v10 = *cur.p10;
    f32x4 v11 = *cur.p11;

    while (true) {
        const int nxt = cell + nwaves;
        const bool has = (nxt < ncells);

        Cell nx;
        f32x4 w00, w01, w10, w11;
        if (has) {
            // Issue next cell's loads BEFORE consuming current cell's values.
            nx = cell_addrs(nxt, lane, fm, rois, H, W, C, R);
            w00 = *nx.p00;
            w01 = *nx.p01;
            w10 = *nx.p10;
            w11 = *nx.p11;
        }

        const float fx = cur.fx, fy = cur.fy;
        const float gx = 1.0f - fx;
        const float gy = 1.0f - fy;
        f32x4 o = (v00 * gx + v01 * fx) * gy + (v10 * gx + v11 * fx) * fy;

        f32x4* po = (f32x4*)(out + (long)cell * C) + lane;
        __builtin_nontemporal_store(o, po);

        if (!has) break;
        cell = nxt;
        cur  = nx;
        v00 = w00; v01 = w01; v10 = w10; v11 = w11;
    }
}

extern "C" void kernel_launch(void* const* d_in, const int* in_sizes, int n_in,
                              void* d_out, int out_size, void* d_ws, size_t ws_size,
                              hipStream_t stream) {
    const float* fm   = (const float*)d_in[0];
    const int*   rois = (const int*)d_in[1];
    float*       out  = (float*)d_out;

    const int B = 4, H = 256, W = 256, C = 256, R = 128;

    roi_pool_kernel<<<NBLK, TPB, 0, stream>>>(fm, rois, out, B, H, W, C, R);
}